// Round 2
// 612.488 us; speedup vs baseline: 1.0102x; 1.0102x over previous
//
#include <hip/hip_runtime.h>
#include <math.h>

// B=262144 rows, N=1e6, R=64, H=128.
// Outputs: logits [B,2] (524288 f32) then loss scalar, concatenated in d_out.
//
// R2 (resubmit after infra failure): timed region = 2GB ws-poison fill
// (~315us, harness, untouchable) + our dispatches. Controllable slice ~300us
// by subtraction vs a ~45us gather roofline (268MB of random 512B Wx rows @
// 6.3TB/s). Previous structure serialized idx-load -> gather -> shfl-reduce
// every iteration, draining the memory queue. This version: ONE coalesced idx
// round-trip per block (indices live in lanes, distributed by __shfl), then
// 24 row-gathers software-pipelined depth-2 in straight-line code so gathers
// stay in flight under the reduce/sigmoid tail.

#define H_DIM 128

#define LOADIT(it, av, bv, wv)                                         \
  {                                                                    \
    const int xi_ = __shfl(vidx, (it), 32);                            \
    const int yi_ = __shfl(vidx, 8 + (it), 32);                        \
    const int ri_ = __shfl(vidx, 16 + (it), 32);                       \
    av = *(const float4*)(Wx + (size_t)xi_ * H_DIM + lane * 4);        \
    bv = *(const float4*)(Wx + (size_t)yi_ * H_DIM + lane * 4);        \
    wv = *(const float4*)(Wr + (size_t)ri_ * H_DIM + lane * 4);        \
  }

#define COMPIT(it, av, bv, wv)                                         \
  {                                                                    \
    const int li_ = __shfl(vidx, 24 + (it), 32);                       \
    float v0 = fminf(6.0f, fmaxf(-6.0f, (wv).x));                      \
    float v1 = fminf(6.0f, fmaxf(-6.0f, (wv).y));                      \
    float v2 = fminf(6.0f, fmaxf(-6.0f, (wv).z));                      \
    float v3 = fminf(6.0f, fmaxf(-6.0f, (wv).w));                      \
    float s0 = 1.0f / (1.0f + __expf(-v0));                            \
    float s1 = 1.0f / (1.0f + __expf(-v1));                            \
    float s2 = 1.0f / (1.0f + __expf(-v2));                            \
    float s3 = 1.0f / (1.0f + __expf(-v3));                            \
    float d = (av).x * (bv).x * (s0 * (1.0f - s0))                     \
            + (av).y * (bv).y * (s1 * (1.0f - s1))                     \
            + (av).z * (bv).z * (s2 * (1.0f - s2))                     \
            + (av).w * (bv).w * (s3 * (1.0f - s3));                    \
    d += __shfl_xor(d, 16, 64);                                        \
    d += __shfl_xor(d, 8, 64);                                         \
    d += __shfl_xor(d, 4, 64);                                         \
    d += __shfl_xor(d, 2, 64);                                         \
    d += __shfl_xor(d, 1, 64);                                         \
    if (lane == 0) {                                                   \
      const float p = 1.0f / (1.0f + __expf(-d));                      \
      const float q = 1.0f - p;                                        \
      *(float2*)(logits + (size_t)(rbase + (it)) * 2) =                \
          make_float2(p, q);                                           \
      const float lse = __logf(__expf(p) + __expf(q));                 \
      lossacc += lse - (li_ == 0 ? p : q);                             \
    }                                                                  \
  }

__global__ __launch_bounds__(256) void fused_kernel(
    const int* __restrict__ x, const int* __restrict__ y,
    const int* __restrict__ r, const int* __restrict__ l,
    const float* __restrict__ Wx, const float* __restrict__ Wr,
    float* __restrict__ logits, float* __restrict__ partials, int B)
{
    const int group = threadIdx.x >> 5;   // 8 groups of 32 lanes
    const int lane  = threadIdx.x & 31;
    const int rbase = blockIdx.x * 64 + group * 8;  // this group's 8 rows

    __shared__ float sloss[8];
    float lossacc = 0.0f;

    // One coalesced round-trip for all indices this group needs:
    // lanes 0-7 hold x[rbase..rbase+7], 8-15 y, 16-23 r, 24-31 l.
    int vidx = 0;
    {
        const int sel = lane >> 3;
        const int ri  = rbase + (lane & 7);
        if (ri < B) {
            const int* __restrict__ p =
                sel == 0 ? x : sel == 1 ? y : sel == 2 ? r : l;
            vidx = p[ri];
        }
    }

    if (rbase + 8 <= B) {
        // Fast path: straight-line, depth-2 pipelined gathers. The compiler
        // is free to deepen the schedule; the only serial dep is vidx.
        float4 a0, b0, w0, a1, b1, w1;
        LOADIT(0, a0, b0, w0)
        LOADIT(1, a1, b1, w1)
        COMPIT(0, a0, b0, w0)
        LOADIT(2, a0, b0, w0)
        COMPIT(1, a1, b1, w1)
        LOADIT(3, a1, b1, w1)
        COMPIT(2, a0, b0, w0)
        LOADIT(4, a0, b0, w0)
        COMPIT(3, a1, b1, w1)
        LOADIT(5, a1, b1, w1)
        COMPIT(4, a0, b0, w0)
        LOADIT(6, a0, b0, w0)
        COMPIT(5, a1, b1, w1)
        LOADIT(7, a1, b1, w1)
        COMPIT(6, a0, b0, w0)
        COMPIT(7, a1, b1, w1)
    } else if (rbase < B) {
        for (int it = 0; it < 8; ++it) {
            if (rbase + it >= B) break;
            float4 ta, tb, tw;
            LOADIT(it, ta, tb, tw)
            COMPIT(it, ta, tb, tw)
        }
    }

    if (lane == 0) sloss[group] = lossacc;
    __syncthreads();
    if (threadIdx.x == 0) {
        float s = 0.0f;
        #pragma unroll
        for (int gi = 0; gi < 8; ++gi) s += sloss[gi];
        partials[blockIdx.x] = s;
    }
}

__global__ __launch_bounds__(256) void reduce_kernel(
    const float* __restrict__ partials, int n, float* __restrict__ out,
    double invB)
{
    __shared__ double sd[256];
    double acc = 0.0;
    for (int i = threadIdx.x; i < n; i += 256) acc += (double)partials[i];
    sd[threadIdx.x] = acc;
    __syncthreads();
    for (int s = 128; s > 0; s >>= 1) {
        if ((int)threadIdx.x < s) sd[threadIdx.x] += sd[threadIdx.x + s];
        __syncthreads();
    }
    if (threadIdx.x == 0) *out = (float)(sd[0] * invB);
}

extern "C" void kernel_launch(void* const* d_in, const int* in_sizes, int n_in,
                              void* d_out, int out_size, void* d_ws,
                              size_t ws_size, hipStream_t stream) {
    const int*   x  = (const int*)d_in[0];
    const int*   y  = (const int*)d_in[1];
    const int*   r  = (const int*)d_in[2];
    const int*   l  = (const int*)d_in[3];
    const float* Wx = (const float*)d_in[4];
    const float* Wr = (const float*)d_in[5];

    const int B = in_sizes[0];

    float* logits   = (float*)d_out;            // [B,2]
    float* loss_out = logits + (size_t)B * 2;   // scalar

    float* partials = (float*)d_ws;             // [NBLK]
    const int NBLK = (B + 63) >> 6;             // one block per 64 rows (4096)

    fused_kernel<<<NBLK, 256, 0, stream>>>(x, y, r, l, Wx, Wr, logits,
                                           partials, B);
    reduce_kernel<<<1, 256, 0, stream>>>(partials, NBLK, loss_out,
                                         1.0 / (double)B);
}